// Round 6
// baseline (221.143 us; speedup 1.0000x reference)
//
#include <hip/hip_runtime.h>
#include <hip/hip_bf16.h>
#include <math.h>

#define BB 8
#define NN 4096
#define FF 100
#define DD 64
#define BKB 256   // K per stage step (1 KB per adj row per step)
#define RT 32     // rows per block tile

typedef __bf16 bf16x8 __attribute__((ext_vector_type(8)));
typedef float f32x4 __attribute__((ext_vector_type(4)));

__device__ __forceinline__ void gload16(const void* g, void* l) {
    __builtin_amdgcn_global_load_lds(
        (const __attribute__((address_space(1))) unsigned int*)g,
        (__attribute__((address_space(3))) unsigned int*)l, 16, 0, 0);
}

// ---------------------------------------------------------------------------
// Kernel A: hT[b][d][m] = bf16( x[b,m,:] @ Wg[:,d] + bg[d] )  (transposed)
// Also zeroes pooled[] (blocks 0-1). (unchanged — verified)
// ---------------------------------------------------------------------------
__global__ __launch_bounds__(256) void kernA(
    const float* __restrict__ x, const float* __restrict__ Wg,
    const float* __restrict__ bg, __bf16* __restrict__ hT,
    float* __restrict__ pooled)
{
    __shared__ float lds[64][65];
    int tid = threadIdx.x;
    int g = blockIdx.x * 256 + tid;
    if (g < BB * DD) pooled[g] = 0.0f;

    int b  = blockIdx.x >> 6;
    int m0 = (blockIdx.x & 63) * 64;
    int d  = tid & 63;
    int mg = tid >> 6;

    float acc[16];
    float bias = bg[d];
    #pragma unroll
    for (int j = 0; j < 16; ++j) acc[j] = bias;

    const float* xbase = x + ((size_t)b * NN + m0 + mg * 16) * FF;
    for (int f4 = 0; f4 < FF / 4; ++f4) {
        float wg0 = Wg[(f4 * 4 + 0) * DD + d];
        float wg1 = Wg[(f4 * 4 + 1) * DD + d];
        float wg2 = Wg[(f4 * 4 + 2) * DD + d];
        float wg3 = Wg[(f4 * 4 + 3) * DD + d];
        #pragma unroll
        for (int j = 0; j < 16; ++j) {
            float4 xv = *reinterpret_cast<const float4*>(xbase + j * FF + f4 * 4);
            acc[j] += xv.x * wg0 + xv.y * wg1 + xv.z * wg2 + xv.w * wg3;
        }
    }
    #pragma unroll
    for (int j = 0; j < 16; ++j) lds[mg * 16 + j][d] = acc[j];
    __syncthreads();

    int lane = tid & 63;
    int dg   = tid >> 6;
    size_t obase = ((size_t)b * DD + dg * 16) * NN + m0 + lane;
    #pragma unroll
    for (int j = 0; j < 16; ++j)
        hT[obase + (size_t)j * NN] = (__bf16)lds[lane][dg * 16 + j];
}

// ---------------------------------------------------------------------------
// Kernel B v5: clump-size experiment. Tile 32 rows x 64 d, BK=256 so every
// global_load_lds covers ONE contiguous 1 KB run of an adj row (vs 256 B
// before) — targets DRAM-activate efficiency. 512 thr (8 waves), dbuf LDS
// 128 KB (1 block/CU), counted vmcnt(8); prefetch of tile t+2 is issued
// after a read-drain barrier so double-buffering is race-free.
// Wave (wr = w>>2) rows [wr*16,+16), (wd = w&3) cols d [wd*16,+16).
// Grid: (128 rowgroups, 8 batches) = 1024 blocks.
// ---------------------------------------------------------------------------
__global__ __launch_bounds__(512) void kernB(
    const float* __restrict__ adj, const __bf16* __restrict__ hT,
    const float* __restrict__ mask, float* __restrict__ pooled)
{
    __shared__ float  aL[2][RT * BKB];    // 2 x 32 KB
    __shared__ __bf16 hL[2][DD * BKB];    // 2 x 32 KB

    int bb  = blockIdx.y;
    int n0  = blockIdx.x * RT;
    int tid = threadIdx.x;
    int w    = tid >> 6;
    int lane = tid & 63;
    int l15  = lane & 15;
    int kg   = lane >> 4;
    int wr   = w >> 2;                    // row half 0..1
    int wd   = w & 3;                     // d quarter 0..3
    int rowL = wr * 16 + l15;             // 0..31
    int dL   = wd * 16 + l15;             // 0..63

    f32x4 acc = {0.f, 0.f, 0.f, 0.f};

    const float*  adjB = adj + ((size_t)bb * NN + n0) * NN;
    const __bf16* hTB  = hT + (size_t)bb * DD * NN;

    auto stage = [&](int buf, int k0) {
        #pragma unroll
        for (int i = 0; i < 4; ++i) {     // adj: 32 rows x 64 granules(16B)
            int p    = i * 512 + tid;     // wave-consecutive => 1 KB/row run
            int row  = p >> 6;
            int slot = p & 63;
            int ss   = slot ^ (row & 15); // involution, within-row permute
            const float* gp = adjB + (size_t)row * NN + k0 + ss * 4;
            gload16(gp, (char*)(&aL[buf][0]) + (size_t)p * 16);
        }
        #pragma unroll
        for (int i = 0; i < 4; ++i) {     // hT: 64 d x 32 granules(16B)
            int p    = i * 512 + tid;
            int d    = p >> 5;
            int slot = p & 31;
            int ss   = slot ^ (d & 15);
            const __bf16* gp = hTB + (size_t)d * NN + k0 + ss * 8;
            gload16(gp, (char*)(&hL[buf][0]) + (size_t)p * 16);
        }
    };

    const int NSTEP = NN / BKB;           // 16
    stage(0, 0);
    stage(1, BKB);

    for (int step = 0; step < NSTEP; ++step) {
        // tile `step` complete; tile step+1's 8 loads stay in flight
        if (step < NSTEP - 1)
            asm volatile("s_waitcnt vmcnt(8) lgkmcnt(0)" ::: "memory");
        else
            asm volatile("s_waitcnt vmcnt(0) lgkmcnt(0)" ::: "memory");
        __builtin_amdgcn_s_barrier();

        int cur = step & 1;
        const float*  aB = &aL[cur][rowL * BKB];
        const __bf16* hB = &hL[cur][(size_t)dL * BKB];
        #pragma unroll
        for (int kk = 0; kk < 8; ++kk) {
            int sa = kk * 8 + kg * 2;     // 16B slot within 1KB adj row
            f32x4 alo = *(const f32x4*)(aB + ((sa    ) ^ l15) * 4);
            f32x4 ahi = *(const f32x4*)(aB + ((sa + 1) ^ l15) * 4);
            bf16x8 af;
            af[0] = (__bf16)alo[0]; af[1] = (__bf16)alo[1];
            af[2] = (__bf16)alo[2]; af[3] = (__bf16)alo[3];
            af[4] = (__bf16)ahi[0]; af[5] = (__bf16)ahi[1];
            af[6] = (__bf16)ahi[2]; af[7] = (__bf16)ahi[3];
            int sb = (kk * 4 + kg) ^ l15; // 16B slot within 512B hT row
            bf16x8 bv = *(const bf16x8*)(hB + sb * 8);
            acc = __builtin_amdgcn_mfma_f32_16x16x32_bf16(af, bv, acc, 0, 0, 0);
        }
        // all my LDS reads done -> barrier -> safe to overwrite buffer `cur`
        asm volatile("s_waitcnt lgkmcnt(0)" ::: "memory");
        __builtin_amdgcn_s_barrier();
        if (step + 2 < NSTEP) stage(cur, (step + 2) * BKB);
    }

    // Epilogue: D layout col = lane&15 (d), row = (lane>>4)*4 + j (n) [m89]
    int rbase = n0 + wr * 16 + kg * 4;
    float s = 0.f;
    #pragma unroll
    for (int j = 0; j < 4; ++j)
        s += fmaxf(acc[j], 0.f) * mask[bb * NN + rbase + j];
    s += __shfl_xor(s, 16);
    s += __shfl_xor(s, 32);
    if (lane < 16)
        atomicAdd(&pooled[bb * DD + wd * 16 + lane], s);
}

// ---------------------------------------------------------------------------
// Kernel C: pooled normalize + time MLP + classifier + sigmoid. 1 block.
// ---------------------------------------------------------------------------
__global__ __launch_bounds__(512) void kernC(
    const float* __restrict__ mask, const float* __restrict__ t_in,
    const float* __restrict__ Wt, const float* __restrict__ bt,
    const float* __restrict__ W0, const float* __restrict__ b0,
    const float* __restrict__ W1, const float* __restrict__ b1,
    const float* __restrict__ W2, const float* __restrict__ b2,
    const float* __restrict__ pooled, float* __restrict__ out)
{
    __shared__ float msum[BB];
    __shared__ float zs[BB][2 * DD];
    __shared__ float z1s[BB][DD];
    __shared__ float z2s[BB][DD];

    int tid  = threadIdx.x;
    int b    = tid >> 6;
    int lane = tid & 63;

    float s = 0.f;
    for (int i = lane; i < NN; i += 64) s += mask[b * NN + i];
    s += __shfl_xor(s, 32); s += __shfl_xor(s, 16);
    s += __shfl_xor(s, 8);  s += __shfl_xor(s, 4);
    s += __shfl_xor(s, 2);  s += __shfl_xor(s, 1);
    if (lane == 0) msum[b] = s;
    __syncthreads();

    float ms  = fmaxf(msum[b], 1.0f);
    float pv  = pooled[b * DD + lane] / ms;
    float tev = t_in[b] * Wt[lane] + bt[lane];
    zs[b][lane]      = pv;
    zs[b][DD + lane] = tev;
    __syncthreads();

    float a = b0[lane];
    for (int f = 0; f < 2 * DD; ++f) a += zs[b][f] * W0[f * DD + lane];
    z1s[b][lane] = fmaxf(a, 0.f);
    __syncthreads();

    a = b1[lane];
    for (int f = 0; f < DD; ++f) a += z1s[b][f] * W1[f * DD + lane];
    z2s[b][lane] = fmaxf(a, 0.f);
    __syncthreads();

    if (lane == 0) {
        float o = b2[0];
        for (int f = 0; f < DD; ++f) o += z2s[b][f] * W2[f];
        out[b] = 1.f / (1.f + expf(-o));
    }
}

// ---------------------------------------------------------------------------
extern "C" void kernel_launch(void* const* d_in, const int* in_sizes, int n_in,
                              void* d_out, int out_size, void* d_ws, size_t ws_size,
                              hipStream_t stream)
{
    const float* x    = (const float*)d_in[0];
    const float* adj  = (const float*)d_in[1];
    const float* mask = (const float*)d_in[2];
    const float* t    = (const float*)d_in[3];
    const float* Wg   = (const float*)d_in[4];
    const float* bg   = (const float*)d_in[5];
    const float* Wt   = (const float*)d_in[6];
    const float* bt   = (const float*)d_in[7];
    const float* W0   = (const float*)d_in[8];
    const float* b0   = (const float*)d_in[9];
    const float* W1   = (const float*)d_in[10];
    const float* b1   = (const float*)d_in[11];
    const float* W2   = (const float*)d_in[12];
    const float* b2   = (const float*)d_in[13];
    float* out = (float*)d_out;

    __bf16* hT    = (__bf16*)d_ws;                                    // 4 MB
    float* pooled = (float*)((char*)d_ws + (size_t)BB * DD * NN * 2); // 2 KB

    kernA<<<BB * NN / 64, 256, 0, stream>>>(x, Wg, bg, hT, pooled);
    kernB<<<dim3(NN / RT, BB), 512, 0, stream>>>(adj, hT, mask, pooled);
    kernC<<<1, 512, 0, stream>>>(mask, t, Wt, bt, W0, b0, W1, b1, W2, b2,
                                 pooled, out);
}

// Round 7
// 178.950 us; speedup vs baseline: 1.2358x; 1.2358x over previous
//
#include <hip/hip_runtime.h>
#include <hip/hip_bf16.h>
#include <math.h>

#define BB 8
#define NN 4096
#define FF 100
#define DD 64
#define BK 64

typedef __bf16 bf16x8 __attribute__((ext_vector_type(8)));
typedef float f32x4 __attribute__((ext_vector_type(4)));

__device__ __forceinline__ void gload16(const void* g, void* l) {
    __builtin_amdgcn_global_load_lds(
        (const __attribute__((address_space(1))) unsigned int*)g,
        (__attribute__((address_space(3))) unsigned int*)l, 16, 0, 0);
}

// ---------------------------------------------------------------------------
// Kernel A: hT[b][d][m] = bf16( x[b,m,:] @ Wg[:,d] + bg[d] )  (transposed)
// Also zeroes pooled[] (blocks 0-1). (unchanged — verified)
// ---------------------------------------------------------------------------
__global__ __launch_bounds__(256) void kernA(
    const float* __restrict__ x, const float* __restrict__ Wg,
    const float* __restrict__ bg, __bf16* __restrict__ hT,
    float* __restrict__ pooled)
{
    __shared__ float lds[64][65];
    int tid = threadIdx.x;
    int g = blockIdx.x * 256 + tid;
    if (g < BB * DD) pooled[g] = 0.0f;

    int b  = blockIdx.x >> 6;
    int m0 = (blockIdx.x & 63) * 64;
    int d  = tid & 63;
    int mg = tid >> 6;

    float acc[16];
    float bias = bg[d];
    #pragma unroll
    for (int j = 0; j < 16; ++j) acc[j] = bias;

    const float* xbase = x + ((size_t)b * NN + m0 + mg * 16) * FF;
    for (int f4 = 0; f4 < FF / 4; ++f4) {
        float wg0 = Wg[(f4 * 4 + 0) * DD + d];
        float wg1 = Wg[(f4 * 4 + 1) * DD + d];
        float wg2 = Wg[(f4 * 4 + 2) * DD + d];
        float wg3 = Wg[(f4 * 4 + 3) * DD + d];
        #pragma unroll
        for (int j = 0; j < 16; ++j) {
            float4 xv = *reinterpret_cast<const float4*>(xbase + j * FF + f4 * 4);
            acc[j] += xv.x * wg0 + xv.y * wg1 + xv.z * wg2 + xv.w * wg3;
        }
    }
    #pragma unroll
    for (int j = 0; j < 16; ++j) lds[mg * 16 + j][d] = acc[j];
    __syncthreads();

    int lane = tid & 63;
    int dg   = tid >> 6;
    size_t obase = ((size_t)b * DD + dg * 16) * NN + m0 + lane;
    #pragma unroll
    for (int j = 0; j < 16; ++j)
        hT[obase + (size_t)j * NN] = (__bf16)lds[lane][dg * 16 + j];
}

// ---------------------------------------------------------------------------
// Kernel B v7 = R5 structure + XCD-aware swizzle (T1).
// Swizzle: linear block id l -> batch bb = l&7 (== XCD id under %8 round-
// robin), rowgroup rg = l>>3. Each XCD serves ONE batch -> its 4 MB hT[bb]
// fits that XCD's L2; hT traffic leaves the shared fabric/L3 path, which
// the R4/R5/R6 invariance implicates as the ~3 TB/s bottleneck.
// Triple-buffer LDS, counted vmcnt(6) (never 0 in loop), 2 blocks/CU.
// ---------------------------------------------------------------------------
__global__ __launch_bounds__(256) void kernB(
    const float* __restrict__ adj, const __bf16* __restrict__ hT,
    const float* __restrict__ mask, float* __restrict__ pooled)
{
    __shared__ float  aL[3][64 * BK];   // 3 x 16 KB
    __shared__ __bf16 hL[3][DD * BK];   // 3 x 8 KB

    int l   = blockIdx.x + gridDim.x * blockIdx.y;   // 0..511
    int bb  = l & 7;                    // batch == XCD (l % 8 round-robin)
    int n0  = (l >> 3) * 64;            // rowgroup
    int tid = threadIdx.x;
    int w    = tid >> 6;
    int lane = tid & 63;
    int l15  = lane & 15;
    int kg   = lane >> 4;
    int rowL = w * 16 + l15;
    int rsw  = rowL & 15;               // adj swizzle key
    int dsw  = l15 & 7;                 // hT swizzle key

    f32x4 acc[4];
    #pragma unroll
    for (int c = 0; c < 4; ++c) acc[c] = (f32x4){0.f, 0.f, 0.f, 0.f};

    const float*  adjB = adj + ((size_t)bb * NN + n0) * NN;
    const __bf16* hTB  = hT + (size_t)bb * DD * NN;

    auto stage = [&](int buf, int k0) {
        #pragma unroll
        for (int i = 0; i < 4; ++i) {              // adj: 64 rows x 256 B
            int p    = i * 256 + tid;
            int row  = p >> 4;
            int slot = p & 15;
            int ss   = slot ^ (row & 15);
            const float* gp = adjB + (size_t)row * NN + k0 + ss * 4;
            gload16(gp, (char*)(&aL[buf][0]) + (size_t)p * 16);
        }
        #pragma unroll
        for (int i = 0; i < 2; ++i) {              // hT: 64 d x 128 B
            int p    = i * 256 + tid;
            int d    = p >> 3;
            int slot = p & 7;
            int ss   = slot ^ (d & 7);
            const __bf16* gp = hTB + (size_t)d * NN + k0 + ss * 8;
            gload16(gp, (char*)(&hL[buf][0]) + (size_t)p * 16);
        }
    };

    const int NSTEP = NN / BK;          // 64
    stage(0, 0);
    stage(1, BK);

    for (int step = 0; step < NSTEP; ++step) {
        // wait for tile `step` only; tile step+1's 6 loads stay in flight
        if (step < NSTEP - 1) {
            asm volatile("s_waitcnt vmcnt(6) lgkmcnt(0)" ::: "memory");
        } else {
            asm volatile("s_waitcnt vmcnt(0) lgkmcnt(0)" ::: "memory");
        }
        __builtin_amdgcn_s_barrier();
        if (step + 2 < NSTEP) stage((step + 2) % 3, (step + 2) * BK);

        int cur = step % 3;
        const float*  aB = &aL[cur][rowL * BK];
        const __bf16* hB = &hL[cur][0];
        #pragma unroll
        for (int kk = 0; kk < 2; ++kk) {
            int s0 = kk * 8 + kg * 2;
            f32x4 alo = *(const f32x4*)(aB + ((s0    ) ^ rsw) * 4);
            f32x4 ahi = *(const f32x4*)(aB + ((s0 + 1) ^ rsw) * 4);
            bf16x8 af;
            af[0] = (__bf16)alo[0]; af[1] = (__bf16)alo[1];
            af[2] = (__bf16)alo[2]; af[3] = (__bf16)alo[3];
            af[4] = (__bf16)ahi[0]; af[5] = (__bf16)ahi[1];
            af[6] = (__bf16)ahi[2]; af[7] = (__bf16)ahi[3];
            int slB = (kk * 4 + kg) ^ dsw;
            #pragma unroll
            for (int c = 0; c < 4; ++c) {
                const __bf16* bp = hB + (c * 16 + l15) * BK + slB * 8;
                acc[c] = __builtin_amdgcn_mfma_f32_16x16x32_bf16(
                    af, *(const bf16x8*)bp, acc[c], 0, 0, 0);
            }
        }
    }

    // Epilogue: D layout col = lane&15, row = (lane>>4)*4 + j  [m89 verified]
    float mk[4];
    int growbase = n0 + w * 16 + kg * 4;
    #pragma unroll
    for (int j = 0; j < 4; ++j) mk[j] = mask[bb * NN + growbase + j];
    #pragma unroll
    for (int c = 0; c < 4; ++c) {
        float s = 0.f;
        #pragma unroll
        for (int j = 0; j < 4; ++j) s += fmaxf(acc[c][j], 0.f) * mk[j];
        s += __shfl_xor(s, 16);
        s += __shfl_xor(s, 32);
        if (lane < 16)
            atomicAdd(&pooled[bb * DD + c * 16 + lane], s);
    }
}

// ---------------------------------------------------------------------------
// Kernel C: pooled normalize + time MLP + classifier + sigmoid. 1 block.
// ---------------------------------------------------------------------------
__global__ __launch_bounds__(512) void kernC(
    const float* __restrict__ mask, const float* __restrict__ t_in,
    const float* __restrict__ Wt, const float* __restrict__ bt,
    const float* __restrict__ W0, const float* __restrict__ b0,
    const float* __restrict__ W1, const float* __restrict__ b1,
    const float* __restrict__ W2, const float* __restrict__ b2,
    const float* __restrict__ pooled, float* __restrict__ out)
{
    __shared__ float msum[BB];
    __shared__ float zs[BB][2 * DD];
    __shared__ float z1s[BB][DD];
    __shared__ float z2s[BB][DD];

    int tid  = threadIdx.x;
    int b    = tid >> 6;
    int lane = tid & 63;

    float s = 0.f;
    for (int i = lane; i < NN; i += 64) s += mask[b * NN + i];
    s += __shfl_xor(s, 32); s += __shfl_xor(s, 16);
    s += __shfl_xor(s, 8);  s += __shfl_xor(s, 4);
    s += __shfl_xor(s, 2);  s += __shfl_xor(s, 1);
    if (lane == 0) msum[b] = s;
    __syncthreads();

    float ms  = fmaxf(msum[b], 1.0f);
    float pv  = pooled[b * DD + lane] / ms;
    float tev = t_in[b] * Wt[lane] + bt[lane];
    zs[b][lane]      = pv;
    zs[b][DD + lane] = tev;
    __syncthreads();

    float a = b0[lane];
    for (int f = 0; f < 2 * DD; ++f) a += zs[b][f] * W0[f * DD + lane];
    z1s[b][lane] = fmaxf(a, 0.f);
    __syncthreads();

    a = b1[lane];
    for (int f = 0; f < DD; ++f) a += z1s[b][f] * W1[f * DD + lane];
    z2s[b][lane] = fmaxf(a, 0.f);
    __syncthreads();

    if (lane == 0) {
        float o = b2[0];
        for (int f = 0; f < DD; ++f) o += z2s[b][f] * W2[f];
        out[b] = 1.f / (1.f + expf(-o));
    }
}

// ---------------------------------------------------------------------------
extern "C" void kernel_launch(void* const* d_in, const int* in_sizes, int n_in,
                              void* d_out, int out_size, void* d_ws, size_t ws_size,
                              hipStream_t stream)
{
    const float* x    = (const float*)d_in[0];
    const float* adj  = (const float*)d_in[1];
    const float* mask = (const float*)d_in[2];
    const float* t    = (const float*)d_in[3];
    const float* Wg   = (const float*)d_in[4];
    const float* bg   = (const float*)d_in[5];
    const float* Wt   = (const float*)d_in[6];
    const float* bt   = (const float*)d_in[7];
    const float* W0   = (const float*)d_in[8];
    const float* b0   = (const float*)d_in[9];
    const float* W1   = (const float*)d_in[10];
    const float* b1   = (const float*)d_in[11];
    const float* W2   = (const float*)d_in[12];
    const float* b2   = (const float*)d_in[13];
    float* out = (float*)d_out;

    __bf16* hT    = (__bf16*)d_ws;                                    // 4 MB
    float* pooled = (float*)((char*)d_ws + (size_t)BB * DD * NN * 2); // 2 KB

    kernA<<<BB * NN / 64, 256, 0, stream>>>(x, Wg, bg, hT, pooled);
    kernB<<<dim3(NN / 64, BB), 256, 0, stream>>>(adj, hT, mask, pooled);
    kernC<<<1, 512, 0, stream>>>(mask, t, Wt, bt, W0, b0, W1, b1, W2, b2,
                                 pooled, out);
}

// Round 8
// 172.867 us; speedup vs baseline: 1.2793x; 1.0352x over previous
//
#include <hip/hip_runtime.h>
#include <hip/hip_bf16.h>
#include <math.h>

#define BB 8
#define NN 4096
#define FF 100
#define DD 64
#define BK 64
#define RT 128    // rows per block tile

typedef __bf16 bf16x8 __attribute__((ext_vector_type(8)));
typedef float f32x4 __attribute__((ext_vector_type(4)));

__device__ __forceinline__ void gload16(const void* g, void* l) {
    __builtin_amdgcn_global_load_lds(
        (const __attribute__((address_space(1))) unsigned int*)g,
        (__attribute__((address_space(3))) unsigned int*)l, 16, 0, 0);
}
// non-temporal variant (cpol NT=2): adj is read-once — keep it from
// evicting the L2-resident hT working set.
__device__ __forceinline__ void gload16nt(const void* g, void* l) {
    __builtin_amdgcn_global_load_lds(
        (const __attribute__((address_space(1))) unsigned int*)g,
        (__attribute__((address_space(3))) unsigned int*)l, 16, 0, 2);
}

// ---------------------------------------------------------------------------
// Kernel A: hT[b][d][m] = bf16( x[b,m,:] @ Wg[:,d] + bg[d] )  (transposed)
// Also zeroes pooled[] (blocks 0-1). (unchanged — verified)
// ---------------------------------------------------------------------------
__global__ __launch_bounds__(256) void kernA(
    const float* __restrict__ x, const float* __restrict__ Wg,
    const float* __restrict__ bg, __bf16* __restrict__ hT,
    float* __restrict__ pooled)
{
    __shared__ float lds[64][65];
    int tid = threadIdx.x;
    int g = blockIdx.x * 256 + tid;
    if (g < BB * DD) pooled[g] = 0.0f;

    int b  = blockIdx.x >> 6;
    int m0 = (blockIdx.x & 63) * 64;
    int d  = tid & 63;
    int mg = tid >> 6;

    float acc[16];
    float bias = bg[d];
    #pragma unroll
    for (int j = 0; j < 16; ++j) acc[j] = bias;

    const float* xbase = x + ((size_t)b * NN + m0 + mg * 16) * FF;
    for (int f4 = 0; f4 < FF / 4; ++f4) {
        float wg0 = Wg[(f4 * 4 + 0) * DD + d];
        float wg1 = Wg[(f4 * 4 + 1) * DD + d];
        float wg2 = Wg[(f4 * 4 + 2) * DD + d];
        float wg3 = Wg[(f4 * 4 + 3) * DD + d];
        #pragma unroll
        for (int j = 0; j < 16; ++j) {
            float4 xv = *reinterpret_cast<const float4*>(xbase + j * FF + f4 * 4);
            acc[j] += xv.x * wg0 + xv.y * wg1 + xv.z * wg2 + xv.w * wg3;
        }
    }
    #pragma unroll
    for (int j = 0; j < 16; ++j) lds[mg * 16 + j][d] = acc[j];
    __syncthreads();

    int lane = tid & 63;
    int dg   = tid >> 6;
    size_t obase = ((size_t)b * DD + dg * 16) * NN + m0 + lane;
    #pragma unroll
    for (int j = 0; j < 16; ++j)
        hT[obase + (size_t)j * NN] = (__bf16)lds[lane][dg * 16 + j];
}

// ---------------------------------------------------------------------------
// Kernel B v8 = R7 + RT=128 (halves hT VMEM traffic: 256 blocks x 512 KB
// = 128 MB) + NT on adj staging (protects per-XCD L2 residency of hT).
// 512 thr (8 waves), wave w: rows [w*16,+16), all 64 d (4 accs).
// Triple-buffer LDS 120 KB, counted vmcnt(5) (5 stage instr/thread),
// 1 block/CU, XCD-bijective swizzle (bb = l&7, 32 blocks/XCD).
// ---------------------------------------------------------------------------
__global__ __launch_bounds__(512) void kernB(
    const float* __restrict__ adj, const __bf16* __restrict__ hT,
    const float* __restrict__ mask, float* __restrict__ pooled)
{
    __shared__ float  aL[3][RT * BK];   // 3 x 32 KB
    __shared__ __bf16 hL[3][DD * BK];   // 3 x 8 KB

    int l   = blockIdx.x;               // 0..255
    int bb  = l & 7;                    // batch == XCD (l % 8 round-robin)
    int n0  = (l >> 3) * RT;            // rowgroup base
    int tid = threadIdx.x;
    int w    = tid >> 6;                // 0..7
    int lane = tid & 63;
    int l15  = lane & 15;
    int kg   = lane >> 4;
    int rowL = w * 16 + l15;            // 0..127
    int rsw  = rowL & 15;               // adj swizzle key
    int dsw  = l15 & 7;                 // hT swizzle key

    f32x4 acc[4];
    #pragma unroll
    for (int c = 0; c < 4; ++c) acc[c] = (f32x4){0.f, 0.f, 0.f, 0.f};

    const float*  adjB = adj + ((size_t)bb * NN + n0) * NN;
    const __bf16* hTB  = hT + (size_t)bb * DD * NN;

    auto stage = [&](int buf, int k0) {
        #pragma unroll
        for (int i = 0; i < 4; ++i) {              // adj: 128 rows x 256 B
            int p    = i * 512 + tid;              // granule 0..2047
            int row  = p >> 4;
            int slot = p & 15;
            int ss   = slot ^ (row & 15);
            const float* gp = adjB + (size_t)row * NN + k0 + ss * 4;
            gload16nt(gp, (char*)(&aL[buf][0]) + (size_t)p * 16);
        }
        {                                          // hT: 64 d x 128 B
            int p    = tid;                        // granule 0..511
            int d    = p >> 3;
            int slot = p & 7;
            int ss   = slot ^ (d & 7);
            const __bf16* gp = hTB + (size_t)d * NN + k0 + ss * 8;
            gload16(gp, (char*)(&hL[buf][0]) + (size_t)p * 16);
        }
    };

    const int NSTEP = NN / BK;          // 64
    stage(0, 0);
    stage(1, BK);

    for (int step = 0; step < NSTEP; ++step) {
        // wait for tile `step` only; tile step+1's 5 loads stay in flight
        if (step < NSTEP - 1) {
            asm volatile("s_waitcnt vmcnt(5) lgkmcnt(0)" ::: "memory");
        } else {
            asm volatile("s_waitcnt vmcnt(0) lgkmcnt(0)" ::: "memory");
        }
        __builtin_amdgcn_s_barrier();
        if (step + 2 < NSTEP) stage((step + 2) % 3, (step + 2) * BK);

        int cur = step % 3;
        const float*  aB = &aL[cur][rowL * BK];
        const __bf16* hB = &hL[cur][0];
        #pragma unroll
        for (int kk = 0; kk < 2; ++kk) {
            int s0 = kk * 8 + kg * 2;
            f32x4 alo = *(const f32x4*)(aB + ((s0    ) ^ rsw) * 4);
            f32x4 ahi = *(const f32x4*)(aB + ((s0 + 1) ^ rsw) * 4);
            bf16x8 af;
            af[0] = (__bf16)alo[0]; af[1] = (__bf16)alo[1];
            af[2] = (__bf16)alo[2]; af[3] = (__bf16)alo[3];
            af[4] = (__bf16)ahi[0]; af[5] = (__bf16)ahi[1];
            af[6] = (__bf16)ahi[2]; af[7] = (__bf16)ahi[3];
            int slB = (kk * 4 + kg) ^ dsw;
            #pragma unroll
            for (int c = 0; c < 4; ++c) {
                const __bf16* bp = hB + (c * 16 + l15) * BK + slB * 8;
                acc[c] = __builtin_amdgcn_mfma_f32_16x16x32_bf16(
                    af, *(const bf16x8*)bp, acc[c], 0, 0, 0);
            }
        }
    }

    // Epilogue: D layout col = lane&15, row = (lane>>4)*4 + j  [m89 verified]
    float mk[4];
    int growbase = n0 + w * 16 + kg * 4;
    #pragma unroll
    for (int j = 0; j < 4; ++j) mk[j] = mask[bb * NN + growbase + j];
    #pragma unroll
    for (int c = 0; c < 4; ++c) {
        float s = 0.f;
        #pragma unroll
        for (int j = 0; j < 4; ++j) s += fmaxf(acc[c][j], 0.f) * mk[j];
        s += __shfl_xor(s, 16);
        s += __shfl_xor(s, 32);
        if (lane < 16)
            atomicAdd(&pooled[bb * DD + c * 16 + lane], s);
    }
}

// ---------------------------------------------------------------------------
// Kernel C: pooled normalize + time MLP + classifier + sigmoid. 1 block.
// ---------------------------------------------------------------------------
__global__ __launch_bounds__(512) void kernC(
    const float* __restrict__ mask, const float* __restrict__ t_in,
    const float* __restrict__ Wt, const float* __restrict__ bt,
    const float* __restrict__ W0, const float* __restrict__ b0,
    const float* __restrict__ W1, const float* __restrict__ b1,
    const float* __restrict__ W2, const float* __restrict__ b2,
    const float* __restrict__ pooled, float* __restrict__ out)
{
    __shared__ float msum[BB];
    __shared__ float zs[BB][2 * DD];
    __shared__ float z1s[BB][DD];
    __shared__ float z2s[BB][DD];

    int tid  = threadIdx.x;
    int b    = tid >> 6;
    int lane = tid & 63;

    float s = 0.f;
    for (int i = lane; i < NN; i += 64) s += mask[b * NN + i];
    s += __shfl_xor(s, 32); s += __shfl_xor(s, 16);
    s += __shfl_xor(s, 8);  s += __shfl_xor(s, 4);
    s += __shfl_xor(s, 2);  s += __shfl_xor(s, 1);
    if (lane == 0) msum[b] = s;
    __syncthreads();

    float ms  = fmaxf(msum[b], 1.0f);
    float pv  = pooled[b * DD + lane] / ms;
    float tev = t_in[b] * Wt[lane] + bt[lane];
    zs[b][lane]      = pv;
    zs[b][DD + lane] = tev;
    __syncthreads();

    float a = b0[lane];
    for (int f = 0; f < 2 * DD; ++f) a += zs[b][f] * W0[f * DD + lane];
    z1s[b][lane] = fmaxf(a, 0.f);
    __syncthreads();

    a = b1[lane];
    for (int f = 0; f < DD; ++f) a += z1s[b][f] * W1[f * DD + lane];
    z2s[b][lane] = fmaxf(a, 0.f);
    __syncthreads();

    if (lane == 0) {
        float o = b2[0];
        for (int f = 0; f < DD; ++f) o += z2s[b][f] * W2[f];
        out[b] = 1.f / (1.f + expf(-o));
    }
}

// ---------------------------------------------------------------------------
extern "C" void kernel_launch(void* const* d_in, const int* in_sizes, int n_in,
                              void* d_out, int out_size, void* d_ws, size_t ws_size,
                              hipStream_t stream)
{
    const float* x    = (const float*)d_in[0];
    const float* adj  = (const float*)d_in[1];
    const float* mask = (const float*)d_in[2];
    const float* t    = (const float*)d_in[3];
    const float* Wg   = (const float*)d_in[4];
    const float* bg   = (const float*)d_in[5];
    const float* Wt   = (const float*)d_in[6];
    const float* bt   = (const float*)d_in[7];
    const float* W0   = (const float*)d_in[8];
    const float* b0   = (const float*)d_in[9];
    const float* W1   = (const float*)d_in[10];
    const float* b1   = (const float*)d_in[11];
    const float* W2   = (const float*)d_in[12];
    const float* b2   = (const float*)d_in[13];
    float* out = (float*)d_out;

    __bf16* hT    = (__bf16*)d_ws;                                    // 4 MB
    float* pooled = (float*)((char*)d_ws + (size_t)BB * DD * NN * 2); // 2 KB

    kernA<<<BB * NN / 64, 256, 0, stream>>>(x, Wg, bg, hT, pooled);
    kernB<<<BB * NN / RT, 512, 0, stream>>>(adj, hT, mask, pooled);
    kernC<<<1, 512, 0, stream>>>(mask, t, Wt, bt, W0, b0, W1, b1, W2, b2,
                                 pooled, out);
}